// Round 1
// baseline (78.506 us; speedup 1.0000x reference)
//
#include <hip/hip_runtime.h>
#include <math.h>

#define DIMS 3
#define NPTS 320
#define HID  128
#define RANK 64

// ---------------- Phase 1: per-dim MLP -> f[d][r][n] (DIMS x RANK x NPTS) ----
// One block per (d, n) point, 128 threads = one hidden unit each.
__global__ __launch_bounds__(HID)
void mlp_kernel(const float* __restrict__ xs,
                const float* __restrict__ W0, const float* __restrict__ b0,
                const float* __restrict__ W1, const float* __restrict__ b1,
                const float* __restrict__ W2, const float* __restrict__ b2,
                const float* __restrict__ W3, const float* __restrict__ b3,
                float* __restrict__ f) {
    int blk = blockIdx.x;
    int d = blk / NPTS, n = blk % NPTS;
    int j = threadIdx.x;

    __shared__ float ha[HID];
    __shared__ float hb[HID];

    float x = xs[d * NPTS + n];

    // layer 0: (N,1) @ (1,H)
    ha[j] = tanhf(fmaf(x, W0[d * HID + j], b0[d * HID + j]));
    __syncthreads();

    // layer 1: H x H
    {
        float acc = b1[d * HID + j];
        const float* w = W1 + d * HID * HID + j;
        #pragma unroll 8
        for (int k = 0; k < HID; ++k) acc = fmaf(ha[k], w[k * HID], acc);
        hb[j] = tanhf(acc);
    }
    __syncthreads();

    // layer 2: H x H
    {
        float acc = b2[d * HID + j];
        const float* w = W2 + d * HID * HID + j;
        #pragma unroll 8
        for (int k = 0; k < HID; ++k) acc = fmaf(hb[k], w[k * HID], acc);
        ha[j] = tanhf(acc);
    }
    __syncthreads();

    // layer 3: H x R (only 64 outputs)
    if (j < RANK) {
        float acc = b3[d * RANK + j];
        const float* w = W3 + d * HID * RANK + j;
        #pragma unroll 8
        for (int k = 0; k < HID; ++k) acc = fmaf(ha[k], w[k * RANK], acc);
        // f[d][r][n]
        f[(d * RANK + j) * NPTS + n] = acc;
    }
}

// ---------------- Phase 2: CP reconstruction --------------------------------
// out[a,b,c] = sum_r f0[r,a] * f1[r,b] * f2[r,c]
// Block: one a (blockIdx.y), one 64-wide b chunk (blockIdx.x), all 320 c.
// 256 threads, per-thread tile: 4 b x 20 c (5 float4 strips, stride 64).
// K=64 processed in two halves of 32 so LDS stays at 48 KB.
__global__ __launch_bounds__(256, 2)
void cp_kernel(const float* __restrict__ f, float* __restrict__ out) {
    const int a  = blockIdx.y;
    const int b0 = blockIdx.x * 64;
    const int tx = threadIdx.x;
    const int cg = tx & 15;   // c group: c = cg*4 + k*64, k = 0..4
    const int bg = tx >> 4;   // b group: b = b0 + bg*4 + i, i = 0..3

    __shared__ float f2s[32][NPTS];   // 40 KB
    __shared__ float gs[32][64];      // 8 KB

    const float* __restrict__ f0 = f;
    const float* __restrict__ f1 = f + RANK * NPTS;
    const float* __restrict__ f2 = f + 2 * RANK * NPTS;

    float acc[4][5][4];
    #pragma unroll
    for (int i = 0; i < 4; ++i)
        #pragma unroll
        for (int k = 0; k < 5; ++k)
            #pragma unroll
            for (int j = 0; j < 4; ++j) acc[i][k][j] = 0.0f;

    for (int half = 0; half < 2; ++half) {
        const int rbase = half * 32;

        // stage f2 chunk: 32x320 floats, contiguous; 10 float4 per thread
        {
            const float4* src = (const float4*)(f2 + rbase * NPTS);
            float4* dst = (float4*)(&f2s[0][0]);
            #pragma unroll
            for (int t = 0; t < 10; ++t) dst[tx + t * 256] = src[tx + t * 256];
        }
        // stage g[r][bb] = f0[r,a] * f1[r, b0+bb]: 2048 vals, 8 per thread
        {
            int i0 = tx * 8;
            int r  = i0 >> 6;
            int bb = i0 & 63;
            float f0v = f0[(rbase + r) * NPTS + a];
            const float* f1p = f1 + (rbase + r) * NPTS + b0 + bb;
            #pragma unroll
            for (int jj = 0; jj < 8; ++jj) gs[r][bb + jj] = f0v * f1p[jj];
        }
        __syncthreads();

        #pragma unroll 4
        for (int r = 0; r < 32; ++r) {
            float4 g4 = *(const float4*)&gs[r][bg * 4];
            float4 fv[5];
            #pragma unroll
            for (int k = 0; k < 5; ++k)
                fv[k] = *(const float4*)&f2s[r][cg * 4 + k * 64];
            const float* gp = (const float*)&g4;
            #pragma unroll
            for (int i = 0; i < 4; ++i) {
                #pragma unroll
                for (int k = 0; k < 5; ++k) {
                    const float* fp = (const float*)&fv[k];
                    #pragma unroll
                    for (int j = 0; j < 4; ++j)
                        acc[i][k][j] = fmaf(gp[i], fp[j], acc[i][k][j]);
                }
            }
        }
        __syncthreads();
    }

    // write out: per thread 4 rows x 5 float4
    #pragma unroll
    for (int i = 0; i < 4; ++i) {
        int b = b0 + bg * 4 + i;
        float4* orow = (float4*)(out + ((size_t)a * NPTS + b) * NPTS);
        #pragma unroll
        for (int k = 0; k < 5; ++k) {
            float4 v;
            v.x = acc[i][k][0]; v.y = acc[i][k][1];
            v.z = acc[i][k][2]; v.w = acc[i][k][3];
            orow[cg + k * 16] = v;
        }
    }
}

extern "C" void kernel_launch(void* const* d_in, const int* in_sizes, int n_in,
                              void* d_out, int out_size, void* d_ws, size_t ws_size,
                              hipStream_t stream) {
    const float* xs = (const float*)d_in[0];
    const float* W0 = (const float*)d_in[1];
    const float* b0 = (const float*)d_in[2];
    const float* W1 = (const float*)d_in[3];
    const float* b1 = (const float*)d_in[4];
    const float* W2 = (const float*)d_in[5];
    const float* b2 = (const float*)d_in[6];
    const float* W3 = (const float*)d_in[7];
    const float* b3 = (const float*)d_in[8];

    float* f = (float*)d_ws;            // DIMS*RANK*NPTS fp32 = 240 KB
    float* out = (float*)d_out;

    mlp_kernel<<<dim3(DIMS * NPTS), dim3(HID), 0, stream>>>(
        xs, W0, b0, W1, b1, W2, b2, W3, b3, f);

    dim3 grid(NPTS / 64, NPTS);         // (5, 320)
    cp_kernel<<<grid, dim3(256), 0, stream>>>(f, out);
}